// Round 1
// baseline (4018.329 us; speedup 1.0000x reference)
//
#include <hip/hip_runtime.h>
#include <math.h>

#define NPTS 4096
#define DIM  32
#define MAXSLOTS 64
#define CJ   128          // columns staged per chunk
#define RPB  32           // rows per block
#define NTHREADS 256
#define YPITCH 36         // padded LDS pitch (floats), 16B aligned, bank-spread

// ws layout in floats
#define WS_N2X   0
#define WS_N2Y   4096
#define WS_PMIN  8192
#define WS_PMAX  10240
#define WS_EPS   12288
#define WS_MODE  12352
#define WS_DUAL  12416
#define DUALSZ   16384    // 4 arrays * 4096  (one parity buffer)

// modes
#define M_SKIP   0
#define M_INIT   1
#define M_AVG    2
#define M_ASSIGN 3

__device__ __forceinline__ float exp2fast(float a){
#if __has_builtin(__builtin_amdgcn_exp2f)
    return __builtin_amdgcn_exp2f(a);
#else
    return exp2f(a);
#endif
}
__device__ __forceinline__ float log2fast(float a){
#if __has_builtin(__builtin_amdgcn_logf)
    return __builtin_amdgcn_logf(a);
#else
    return log2f(a);
#endif
}

// ---------------- norms: 0.5*|row|^2 for x (->ws[0..4095]) and y (->ws[4096..8191])
__global__ void sink_norms(const float* __restrict__ x, const float* __restrict__ y,
                           float* __restrict__ ws)
{
    int row = blockIdx.x * blockDim.x + threadIdx.x;   // 32 blocks * 256 = 8192
    const float* src = (row < NPTS) ? (x + (size_t)row * DIM)
                                    : (y + (size_t)(row - NPTS) * DIM);
    const float4* s4 = (const float4*)src;
    float acc = 0.f;
#pragma unroll
    for (int q = 0; q < 8; q++) {
        float4 v = s4[q];
        acc += v.x*v.x + v.y*v.y + v.z*v.z + v.w*v.w;
    }
    ws[row] = 0.5f * acc;   // n2x at 0, n2y at 4096: contiguous
}

// ---------------- per-dim min/max partials over concat(x,y)
__global__ void sink_minmax(const float* __restrict__ x, const float* __restrict__ y,
                            float* __restrict__ ws)
{
    __shared__ float2 mm[8][32];
    int t = threadIdx.x;
    int d = t & 31, rg = t >> 5;
    float mn = 3.4e38f, mx = -3.4e38f;
#pragma unroll
    for (int k = 0; k < 16; k++) {
        int row = blockIdx.x * 128 + k * 8 + rg;
        const float* src = (row < NPTS) ? (x + (size_t)row * DIM)
                                        : (y + (size_t)(row - NPTS) * DIM);
        float v = src[d];
        mn = fminf(mn, v); mx = fmaxf(mx, v);
    }
    mm[rg][d] = make_float2(mn, mx);
    __syncthreads();
    if (t < 32) {
        float2 a = mm[0][t];
#pragma unroll
        for (int g = 1; g < 8; g++) {
            float2 b = mm[g][t];
            a.x = fminf(a.x, b.x); a.y = fmaxf(a.y, b.y);
        }
        ws[WS_PMIN + blockIdx.x * 32 + t] = a.x;
        ws[WS_PMAX + blockIdx.x * 32 + t] = a.y;
    }
}

// ---------------- schedule: diameter -> eps list + mode per slot (device-side)
__global__ void sink_sched(float* __restrict__ ws)
{
    __shared__ float mins[32], maxs[32];
    int t = threadIdx.x;
    if (t < 32) {
        float mn = 3.4e38f, mx = -3.4e38f;
        for (int b = 0; b < 64; b++) {
            mn = fminf(mn, ws[WS_PMIN + b * 32 + t]);
            mx = fmaxf(mx, ws[WS_PMAX + b * 32 + t]);
        }
        mins[t] = mn; maxs[t] = mx;
    }
    __syncthreads();
    if (t == 0) {
        float dia2 = 0.f;
        for (int d = 0; d < 32; d++) {
            float df = maxs[d] - mins[d];
            dia2 += df * df;
        }
        float dia = sqrtf(dia2);
        float* eps = ws + WS_EPS;
        int*  mode = (int*)(ws + WS_MODE);
        double ld    = log((double)dia);
        double start = 2.0 * ld;
        double stop  = 2.0 * log(0.5);
        double step  = 2.0 * log(0.9);
        int K = (int)ceil((stop - start) / step);   // np.arange length
        if (K < 0) K = 0;
        if (K > MAXSLOTS - 5) K = MAXSLOTS - 5;
        // slot 0: init at eps0 = d^2 (duals ignored)
        eps[0] = dia * dia; mode[0] = M_INIT;
        // averaged loop over eps_list = [d^2] + exp(arange) + [blur^2]
        eps[1] = dia * dia; mode[1] = M_AVG;
        for (int k = 0; k < K; k++) {
            eps[2 + k] = (float)exp(start + step * (double)k);
            mode[2 + k] = M_AVG;
        }
        eps[2 + K] = 0.25f; mode[2 + K] = M_AVG;
        // final extrapolation (assign) at blur^2
        eps[3 + K] = 0.25f; mode[3 + K] = M_ASSIGN;
        for (int s = 4 + K; s < MAXSLOTS; s++) { eps[s] = 0.25f; mode[s] = M_SKIP; }
    }
}

// ---------------- the fused softmin iteration
// grid = 4 matrices * 128 row-tiles = 512 blocks, 256 threads
// thread: rg = t&7 (owns 4 rows), jl = t>>3 (32 column lanes)
__global__ __launch_bounds__(NTHREADS, 2) void sink_iter(
    const float* __restrict__ x, const float* __restrict__ y,
    float* __restrict__ ws, int slot)
{
    const int t = threadIdx.x;
    const int mode = ((const int*)(ws + WS_MODE))[slot];

    if (mode == M_SKIP) {
        const float* src = ws + WS_DUAL + (slot & 1) * DUALSZ;
        float*       dst = ws + WS_DUAL + ((slot + 1) & 1) * DUALSZ;
        int idx = blockIdx.x * NTHREADS + t;
        if (idx < DUALSZ) dst[idx] = src[idx];
        return;
    }

    const float eps     = ws[WS_EPS + slot];
    const float inv_eps = 1.0f / eps;
    const float L2E     = 1.4426950408889634f;
    const float LN2     = 0.6931471805599453f;
    const float ie2     = inv_eps * L2E;
    const float hbase   = -8.317766166719343f;     // -ln(4096)
    const float don     = (mode == M_INIT) ? 0.0f : 1.0f;

    const int bm   = blockIdx.x >> 7;     // matrix: 0=xy 1=yx 2=xx 3=yy
    const int tile = blockIdx.x & 127;

    const float* rowsrc = (bm == 1 || bm == 3) ? y : x;
    const float* colsrc = (bm == 0 || bm == 3) ? y : x;
    const float* rn2 = ws + ((bm == 1 || bm == 3) ? WS_N2Y : WS_N2X);
    const float* cn2 = ws + ((bm == 0 || bm == 3) ? WS_N2Y : WS_N2X);

    const float* bufold = ws + WS_DUAL + (slot & 1) * DUALSZ;
    float*       bufnew = ws + WS_DUAL + ((slot + 1) & 1) * DUALSZ;
    const int dualsel = (bm == 0) ? 1 : (bm == 1) ? 0 : bm;   // {1,0,2,3}
    const float* dual   = bufold + dualsel * NPTS;
    const float* oldout = bufold + bm * NPTS;
    float*       out    = bufnew + bm * NPTS;

    __shared__ float  ys[CJ * YPITCH];     // 18432 B
    __shared__ float  hps[CJ];
    __shared__ float  xs[RPB * DIM];       // 4096 B
    __shared__ float2 parts[4][8][4];      // 1 KB

    // stage the 32-row x-tile (contiguous 4 KB), then pull 4 rows into registers
    {
        const float4* xsrc4 = (const float4*)(rowsrc + (size_t)tile * RPB * DIM);
        ((float4*)xs)[t] = xsrc4[t];       // 256 float4 = 4 KB
    }
    __syncthreads();

    const int rg = t & 7;
    const int jl = t >> 3;

    float4 xf4[4][8];
#pragma unroll
    for (int rr = 0; rr < 4; rr++) {
        const float4* xr = (const float4*)(xs + (rg * 4 + rr) * DIM);
#pragma unroll
        for (int dq = 0; dq < 8; dq++) xf4[rr][dq] = xr[dq];
    }

    float m4[4] = {-INFINITY, -INFINITY, -INFINITY, -INFINITY};
    float s4[4] = {0.f, 0.f, 0.f, 0.f};

    for (int c0 = 0; c0 < NPTS; c0 += CJ) {
        __syncthreads();
        // stage y chunk: CJ cols * 32 floats, contiguous from global, padded in LDS
        const float4* src4 = (const float4*)(colsrc + (size_t)c0 * DIM);
#pragma unroll
        for (int q = 0; q < 4; q++) {
            int idx = t + q * NTHREADS;        // 0..1023
            int c = idx >> 3, dq = idx & 7;
            ((float4*)(ys + c * YPITCH))[dq] = src4[idx];
        }
        if (t < CJ) {
            int j = c0 + t;
            hps[t] = (hbase + (don * dual[j] - cn2[j]) * inv_eps) * L2E;
        }
        __syncthreads();

#pragma unroll
        for (int k = 0; k < CJ / 32; k++) {
            const int cc = jl + k * 32;
            const float4* yrow = (const float4*)(ys + cc * YPITCH);
            const float hp = hps[cc];
            float d0 = 0.f, d1 = 0.f, d2 = 0.f, d3 = 0.f;
#pragma unroll
            for (int dg = 0; dg < 8; dg++) {
                float4 yv = yrow[dg];
                d0 = fmaf(xf4[0][dg].x, yv.x, d0); d0 = fmaf(xf4[0][dg].y, yv.y, d0);
                d0 = fmaf(xf4[0][dg].z, yv.z, d0); d0 = fmaf(xf4[0][dg].w, yv.w, d0);
                d1 = fmaf(xf4[1][dg].x, yv.x, d1); d1 = fmaf(xf4[1][dg].y, yv.y, d1);
                d1 = fmaf(xf4[1][dg].z, yv.z, d1); d1 = fmaf(xf4[1][dg].w, yv.w, d1);
                d2 = fmaf(xf4[2][dg].x, yv.x, d2); d2 = fmaf(xf4[2][dg].y, yv.y, d2);
                d2 = fmaf(xf4[2][dg].z, yv.z, d2); d2 = fmaf(xf4[2][dg].w, yv.w, d2);
                d3 = fmaf(xf4[3][dg].x, yv.x, d3); d3 = fmaf(xf4[3][dg].y, yv.y, d3);
                d3 = fmaf(xf4[3][dg].z, yv.z, d3); d3 = fmaf(xf4[3][dg].w, yv.w, d3);
            }
            // online LSE update (base-2 domain), branchless
            {
                float v = fmaf(d0, ie2, hp); float nm = fmaxf(m4[0], v);
                s4[0] = s4[0] * exp2fast(m4[0] - nm) + exp2fast(v - nm); m4[0] = nm;
            }
            {
                float v = fmaf(d1, ie2, hp); float nm = fmaxf(m4[1], v);
                s4[1] = s4[1] * exp2fast(m4[1] - nm) + exp2fast(v - nm); m4[1] = nm;
            }
            {
                float v = fmaf(d2, ie2, hp); float nm = fmaxf(m4[2], v);
                s4[2] = s4[2] * exp2fast(m4[2] - nm) + exp2fast(v - nm); m4[2] = nm;
            }
            {
                float v = fmaf(d3, ie2, hp); float nm = fmaxf(m4[3], v);
                s4[3] = s4[3] * exp2fast(m4[3] - nm) + exp2fast(v - nm); m4[3] = nm;
            }
        }
    }

    // merge across the 8 column-lanes within each wave (jl bits are lane bits 3,4,5)
#pragma unroll
    for (int w = 8; w <= 32; w <<= 1) {
#pragma unroll
        for (int r = 0; r < 4; r++) {
            float om = __shfl_xor(m4[r], w, 64);
            float os = __shfl_xor(s4[r], w, 64);
            float nm = fmaxf(m4[r], om);
            s4[r] = s4[r] * exp2fast(m4[r] - nm) + os * exp2fast(om - nm);
            m4[r] = nm;
        }
    }
    // cross-wave merge via LDS
    const int lane = t & 63, wv = t >> 6;
    if (lane < 8) {
#pragma unroll
        for (int r = 0; r < 4; r++) parts[wv][lane][r] = make_float2(m4[r], s4[r]);
    }
    __syncthreads();
    if (t < 32) {
        const int rg2 = t >> 2, r2 = t & 3;
        float2 p0 = parts[0][rg2][r2];
        float m = p0.x, s = p0.y;
#pragma unroll
        for (int w = 1; w < 4; w++) {
            float2 p = parts[w][rg2][r2];
            float nm = fmaxf(m, p.x);
            s = s * exp2fast(m - nm) + p.y * exp2fast(p.x - nm);
            m = nm;
        }
        const float lse = LN2 * (m + log2fast(s));  // natural-log LSE
        const int row = tile * RPB + t;              // rg2*4+r2 == t
        const float ft = rn2[row] - eps * lse;
        out[row] = (mode == M_AVG) ? 0.5f * (oldout[row] + ft) : ft;
    }
}

// ---------------- final: mean(f_ba - f_aa) + mean(g_ab - g_bb)
__global__ void sink_reduce(const float* __restrict__ ws, float* __restrict__ outp)
{
    __shared__ float red[NTHREADS];
    const float* b = ws + WS_DUAL;   // parity 0 after 64 slots
    int t = threadIdx.x;
    float acc = 0.f;
    for (int i = t; i < NPTS; i += NTHREADS)
        acc += (b[i] - b[2 * NPTS + i]) + (b[NPTS + i] - b[3 * NPTS + i]);
    red[t] = acc;
    __syncthreads();
    for (int s = NTHREADS / 2; s > 0; s >>= 1) {
        if (t < s) red[t] += red[t + s];
        __syncthreads();
    }
    if (t == 0) outp[0] = red[0] * (1.0f / (float)NPTS);
}

extern "C" void kernel_launch(void* const* d_in, const int* in_sizes, int n_in,
                              void* d_out, int out_size, void* d_ws, size_t ws_size,
                              hipStream_t stream)
{
    const float* x = (const float*)d_in[0];
    const float* y = (const float*)d_in[1];
    float* ws  = (float*)d_ws;
    float* out = (float*)d_out;

    hipLaunchKernelGGL(sink_norms,  dim3(32), dim3(NTHREADS), 0, stream, x, y, ws);
    hipLaunchKernelGGL(sink_minmax, dim3(64), dim3(NTHREADS), 0, stream, x, y, ws);
    hipLaunchKernelGGL(sink_sched,  dim3(1),  dim3(NTHREADS), 0, stream, ws);
    for (int s = 0; s < MAXSLOTS; s++)
        hipLaunchKernelGGL(sink_iter, dim3(512), dim3(NTHREADS), 0, stream, x, y, ws, s);
    hipLaunchKernelGGL(sink_reduce, dim3(1), dim3(NTHREADS), 0, stream, ws, out);
}

// Round 2
// 1640.088 us; speedup vs baseline: 2.4501x; 2.4501x over previous
//
#include <hip/hip_runtime.h>
#include <math.h>

#define NPTS 4096
#define DIM  32
#define MAXSLOTS 56
#define NTHREADS 256
#define ITHREADS 512
#define NELEM 131072      // 4096*32

// ws layout in floats
#define WS_N2X   0
#define WS_N2Y   4096
#define WS_PMIN  8192
#define WS_PMAX  10240
#define WS_EPS   12288
#define WS_MODE  12352
#define WS_DUAL  12416
#define DUALSZ   16384    // 4 arrays * 4096 (one parity buffer)
#define WS_BF    45184    // bf16 pack area: 4*131072 ushorts = 1 MB

// modes
#define M_SKIP   0
#define M_INIT   1
#define M_AVG    2
#define M_ASSIGN 3

typedef short short8 __attribute__((ext_vector_type(8)));
typedef float f32x4  __attribute__((ext_vector_type(4)));

__device__ __forceinline__ float exp2fast(float a){
#if __has_builtin(__builtin_amdgcn_exp2f)
    return __builtin_amdgcn_exp2f(a);
#else
    return exp2f(a);
#endif
}
__device__ __forceinline__ float log2fast(float a){
#if __has_builtin(__builtin_amdgcn_logf)
    return __builtin_amdgcn_logf(a);
#else
    return log2f(a);
#endif
}

// ---------------- norms: 0.5*|row|^2 for x and y
__global__ void sink_norms(const float* __restrict__ x, const float* __restrict__ y,
                           float* __restrict__ ws)
{
    int row = blockIdx.x * blockDim.x + threadIdx.x;   // 32 blocks * 256 = 8192
    const float* src = (row < NPTS) ? (x + (size_t)row * DIM)
                                    : (y + (size_t)(row - NPTS) * DIM);
    const float4* s4 = (const float4*)src;
    float acc = 0.f;
#pragma unroll
    for (int q = 0; q < 8; q++) {
        float4 v = s4[q];
        acc += v.x*v.x + v.y*v.y + v.z*v.z + v.w*v.w;
    }
    ws[row] = 0.5f * acc;
}

// ---------------- split-bf16 prepack: x,y -> {hi,lo} bf16 row-major
// layout (ushort base bf): xhi[0..NELEM) xlo[NELEM..2N) yhi[2N..3N) ylo[3N..4N)
__global__ void sink_prep(const float* __restrict__ x, const float* __restrict__ y,
                          unsigned short* __restrict__ bf)
{
    int tid = blockIdx.x * 256 + threadIdx.x;          // 32768 threads, 8 elems each
    int e = tid * 8;
    const float* src = (e < NELEM) ? (x + e) : (y + (e - NELEM));
    float4 v0 = ((const float4*)src)[0];
    float4 v1 = ((const float4*)src)[1];
    float vs[8] = {v0.x, v0.y, v0.z, v0.w, v1.x, v1.y, v1.z, v1.w};
    unsigned int hi_off = (e < NELEM) ? (unsigned)e : (unsigned)(e + NELEM);
    short hv[8], lv[8];
#pragma unroll
    for (int i = 0; i < 8; i++) {
        float f = vs[i];
        unsigned int u = __float_as_uint(f);
        unsigned int r = u + 0x7fffu + ((u >> 16) & 1u);   // RNE to bf16
        unsigned short h = (unsigned short)(r >> 16);
        float hf = __uint_as_float(((unsigned int)h) << 16);
        float l = f - hf;
        unsigned int ul = __float_as_uint(l);
        unsigned int rl = ul + 0x7fffu + ((ul >> 16) & 1u);
        hv[i] = (short)(r >> 16);
        lv[i] = (short)(rl >> 16);
        (void)h; (void)hf;
    }
    short8 hvec = {hv[0],hv[1],hv[2],hv[3],hv[4],hv[5],hv[6],hv[7]};
    short8 lvec = {lv[0],lv[1],lv[2],lv[3],lv[4],lv[5],lv[6],lv[7]};
    *(short8*)((short*)bf + hi_off)         = hvec;
    *(short8*)((short*)bf + hi_off + NELEM) = lvec;
}

// ---------------- per-dim min/max partials over concat(x,y)
__global__ void sink_minmax(const float* __restrict__ x, const float* __restrict__ y,
                            float* __restrict__ ws)
{
    __shared__ float2 mm[8][32];
    int t = threadIdx.x;
    int d = t & 31, rg = t >> 5;
    float mn = 3.4e38f, mx = -3.4e38f;
#pragma unroll
    for (int k = 0; k < 16; k++) {
        int row = blockIdx.x * 128 + k * 8 + rg;
        const float* src = (row < NPTS) ? (x + (size_t)row * DIM)
                                        : (y + (size_t)(row - NPTS) * DIM);
        float v = src[d];
        mn = fminf(mn, v); mx = fmaxf(mx, v);
    }
    mm[rg][d] = make_float2(mn, mx);
    __syncthreads();
    if (t < 32) {
        float2 a = mm[0][t];
#pragma unroll
        for (int g = 1; g < 8; g++) {
            float2 b = mm[g][t];
            a.x = fminf(a.x, b.x); a.y = fmaxf(a.y, b.y);
        }
        ws[WS_PMIN + blockIdx.x * 32 + t] = a.x;
        ws[WS_PMAX + blockIdx.x * 32 + t] = a.y;
    }
}

// ---------------- schedule: diameter -> eps list + mode per slot
__global__ void sink_sched(float* __restrict__ ws)
{
    __shared__ float mins[32], maxs[32];
    int t = threadIdx.x;
    if (t < 32) {
        float mn = 3.4e38f, mx = -3.4e38f;
        for (int b = 0; b < 64; b++) {
            mn = fminf(mn, ws[WS_PMIN + b * 32 + t]);
            mx = fmaxf(mx, ws[WS_PMAX + b * 32 + t]);
        }
        mins[t] = mn; maxs[t] = mx;
    }
    __syncthreads();
    if (t == 0) {
        float dia2 = 0.f;
        for (int d = 0; d < 32; d++) {
            float df = maxs[d] - mins[d];
            dia2 += df * df;
        }
        float dia = sqrtf(dia2);
        float* eps = ws + WS_EPS;
        int*  mode = (int*)(ws + WS_MODE);
        double ld    = log((double)dia);
        double start = 2.0 * ld;
        double stop  = 2.0 * log(0.5);
        double step  = 2.0 * log(0.9);
        int K = (int)ceil((stop - start) / step);
        if (K < 0) K = 0;
        if (K > MAXSLOTS - 5) K = MAXSLOTS - 5;
        eps[0] = dia * dia; mode[0] = M_INIT;
        eps[1] = dia * dia; mode[1] = M_AVG;
        for (int k = 0; k < K; k++) {
            eps[2 + k] = (float)exp(start + step * (double)k);
            mode[2 + k] = M_AVG;
        }
        eps[2 + K] = 0.25f; mode[2 + K] = M_AVG;
        eps[3 + K] = 0.25f; mode[3 + K] = M_ASSIGN;
        for (int s = 4 + K; s < MAXSLOTS; s++) { eps[s] = 0.25f; mode[s] = M_SKIP; }
    }
}

// ---------------- fused softmin iteration (MFMA split-bf16)
// grid = 4 matrices * 256 row-tiles = 1024 blocks, 512 threads (8 waves)
// block: one 16-row tile; wave w handles cols [w*512, (w+1)*512)
__global__ __launch_bounds__(ITHREADS, 6) void sink_iter(float* __restrict__ ws, int slot)
{
    const int t = threadIdx.x;
    const int mode = ((const int*)(ws + WS_MODE))[slot];

    if (mode == M_SKIP) {
        int idx = blockIdx.x * ITHREADS + t;
        if (idx < DUALSZ)
            ws[WS_DUAL + ((slot + 1) & 1) * DUALSZ + idx] =
                ws[WS_DUAL + (slot & 1) * DUALSZ + idx];
        return;
    }

    const float eps     = ws[WS_EPS + slot];
    const float inv_eps = 1.0f / eps;
    const float L2E     = 1.4426950408889634f;
    const float LN2     = 0.6931471805599453f;
    const float ie2     = inv_eps * L2E;
    const float hbase   = -8.317766166719343f;   // -ln(4096)
    const float don     = (mode == M_INIT) ? 0.0f : 1.0f;

    const int bm   = blockIdx.x >> 8;     // 0=xy 1=yx 2=xx 3=yy
    const int tile = blockIdx.x & 255;
    const int rowIsX = (bm == 0 || bm == 2);
    const int colIsX = (bm == 1 || bm == 2);

    const short* bf = (const short*)(ws + WS_BF);
    const short* rbase = bf + (rowIsX ? 0 : 2 * NELEM);
    const short* cbase = bf + (colIsX ? 0 : 2 * NELEM);
    const float* rn2 = ws + (rowIsX ? WS_N2X : WS_N2Y);
    const float* cn2 = ws + (colIsX ? WS_N2X : WS_N2Y);

    const float* bufold = ws + WS_DUAL + (slot & 1) * DUALSZ;
    float*       bufnew = ws + WS_DUAL + ((slot + 1) & 1) * DUALSZ;
    const int dualsel = (bm == 0) ? 1 : (bm == 1) ? 0 : bm;   // {1,0,2,3}
    const float* dual   = bufold + dualsel * NPTS;
    const float* oldout = bufold + bm * NPTS;
    float*       out    = bufnew + bm * NPTS;

    __shared__ float  hps[NPTS];          // 16 KB
    __shared__ float2 parts[8][16];       // 1 KB

    // build hp[j] for all 4096 cols (coalesced)
#pragma unroll
    for (int q = 0; q < 8; q++) {
        int j = t + q * ITHREADS;
        hps[j] = (hbase + fmaf(don, dual[j], -cn2[j]) * inv_eps) * L2E;
    }

    const int lane = t & 63;
    const int wv   = t >> 6;
    const int lr   = lane & 15;          // A-row / B-col within tile
    const int lk   = (lane >> 4) * 8;    // k offset (8 contiguous bf16)

    // A fragments (persistent)
    const int arow = tile * 16 + lr;
    const short8 ahi = *(const short8*)(rbase + arow * DIM + lk);
    const short8 alo = *(const short8*)(rbase + NELEM + arow * DIM + lk);

    __syncthreads();

    float m0 = -INFINITY, m1 = -INFINITY, m2 = -INFINITY, m3 = -INFINITY;
    float s0 = 0.f, s1 = 0.f, s2 = 0.f, s3 = 0.f;

    const int colbase = wv * 512;
#pragma unroll 2
    for (int ct = 0; ct < 32; ct++) {
        const int col = colbase + ct * 16 + lr;
        const short* bp = cbase + col * DIM + lk;
        const short8 bhi = *(const short8*)(bp);
        const short8 blo = *(const short8*)(bp + NELEM);
        f32x4 c = {0.f, 0.f, 0.f, 0.f};
        c = __builtin_amdgcn_mfma_f32_16x16x32_bf16(alo, bhi, c, 0, 0, 0);
        c = __builtin_amdgcn_mfma_f32_16x16x32_bf16(ahi, blo, c, 0, 0, 0);
        c = __builtin_amdgcn_mfma_f32_16x16x32_bf16(ahi, bhi, c, 0, 0, 0);
        const float hp = hps[col];
        { float v = fmaf(c[0], ie2, hp); float nm = fmaxf(m0, v);
          s0 = fmaf(s0, exp2fast(m0 - nm), exp2fast(v - nm)); m0 = nm; }
        { float v = fmaf(c[1], ie2, hp); float nm = fmaxf(m1, v);
          s1 = fmaf(s1, exp2fast(m1 - nm), exp2fast(v - nm)); m1 = nm; }
        { float v = fmaf(c[2], ie2, hp); float nm = fmaxf(m2, v);
          s2 = fmaf(s2, exp2fast(m2 - nm), exp2fast(v - nm)); m2 = nm; }
        { float v = fmaf(c[3], ie2, hp); float nm = fmaxf(m3, v);
          s3 = fmaf(s3, exp2fast(m3 - nm), exp2fast(v - nm)); m3 = nm; }
    }

    // merge 16 col-lanes (lane bits 0..3); rows live in (lane>>4, reg)
#pragma unroll
    for (int wm = 1; wm <= 8; wm <<= 1) {
        float om, os, nm;
        om = __shfl_xor(m0, wm, 64); os = __shfl_xor(s0, wm, 64);
        nm = fmaxf(m0, om); s0 = fmaf(s0, exp2fast(m0 - nm), os * exp2fast(om - nm)); m0 = nm;
        om = __shfl_xor(m1, wm, 64); os = __shfl_xor(s1, wm, 64);
        nm = fmaxf(m1, om); s1 = fmaf(s1, exp2fast(m1 - nm), os * exp2fast(om - nm)); m1 = nm;
        om = __shfl_xor(m2, wm, 64); os = __shfl_xor(s2, wm, 64);
        nm = fmaxf(m2, om); s2 = fmaf(s2, exp2fast(m2 - nm), os * exp2fast(om - nm)); m2 = nm;
        om = __shfl_xor(m3, wm, 64); os = __shfl_xor(s3, wm, 64);
        nm = fmaxf(m3, om); s3 = fmaf(s3, exp2fast(m3 - nm), os * exp2fast(om - nm)); m3 = nm;
    }
    if (lr == 0) {
        int g = lane >> 4;
        parts[wv][g * 4 + 0] = make_float2(m0, s0);
        parts[wv][g * 4 + 1] = make_float2(m1, s1);
        parts[wv][g * 4 + 2] = make_float2(m2, s2);
        parts[wv][g * 4 + 3] = make_float2(m3, s3);
    }
    __syncthreads();
    if (t < 16) {
        float2 p = parts[0][t];
        float m = p.x, s = p.y;
#pragma unroll
        for (int w2 = 1; w2 < 8; w2++) {
            float2 q = parts[w2][t];
            float nm = fmaxf(m, q.x);
            s = fmaf(s, exp2fast(m - nm), q.y * exp2fast(q.x - nm));
            m = nm;
        }
        const float lse = LN2 * (m + log2fast(s));
        const int row = tile * 16 + t;
        const float ft = rn2[row] - eps * lse;
        out[row] = (mode == M_AVG) ? 0.5f * (oldout[row] + ft) : ft;
    }
}

// ---------------- final: mean(f_ba - f_aa) + mean(g_ab - g_bb)
__global__ void sink_reduce(const float* __restrict__ ws, float* __restrict__ outp)
{
    __shared__ float red[NTHREADS];
    const float* b = ws + WS_DUAL;   // parity 0 after 56 slots
    int t = threadIdx.x;
    float acc = 0.f;
    for (int i = t; i < NPTS; i += NTHREADS)
        acc += (b[i] - b[2 * NPTS + i]) + (b[NPTS + i] - b[3 * NPTS + i]);
    red[t] = acc;
    __syncthreads();
    for (int s = NTHREADS / 2; s > 0; s >>= 1) {
        if (t < s) red[t] += red[t + s];
        __syncthreads();
    }
    if (t == 0) outp[0] = red[0] * (1.0f / (float)NPTS);
}

extern "C" void kernel_launch(void* const* d_in, const int* in_sizes, int n_in,
                              void* d_out, int out_size, void* d_ws, size_t ws_size,
                              hipStream_t stream)
{
    const float* x = (const float*)d_in[0];
    const float* y = (const float*)d_in[1];
    float* ws  = (float*)d_ws;
    float* out = (float*)d_out;

    hipLaunchKernelGGL(sink_norms,  dim3(32),  dim3(NTHREADS), 0, stream, x, y, ws);
    hipLaunchKernelGGL(sink_prep,   dim3(128), dim3(NTHREADS), 0, stream, x, y,
                       (unsigned short*)(ws + WS_BF));
    hipLaunchKernelGGL(sink_minmax, dim3(64),  dim3(NTHREADS), 0, stream, x, y, ws);
    hipLaunchKernelGGL(sink_sched,  dim3(1),   dim3(NTHREADS), 0, stream, ws);
    for (int s = 0; s < MAXSLOTS; s++)
        hipLaunchKernelGGL(sink_iter, dim3(1024), dim3(ITHREADS), 0, stream, ws, s);
    hipLaunchKernelGGL(sink_reduce, dim3(1), dim3(NTHREADS), 0, stream, ws, out);
}